// Round 4
// baseline (103.893 us; speedup 1.0000x reference)
//
#include <hip/hip_runtime.h>
#include <math.h>

// FutureEncoder: B=4, S=2048, D=1024, FUTURE_K=32, fp32 in/out.
// R7: single kernel, no workspace (harness poisons ws ~43us/iter regardless).
// vs R6: (1) split-bf16 conversion via v_cvt_pk_bf16_f32 — 6 VALU ops per
// 2 elements instead of ~22, numerically identical (RNE hi, RNE lo);
// (2) PV is a constant-trip 35-step fully-unrolled loop, branchless
// (invalid weights are already 0 in wm), 2-deep register prefetch with
// static 3-slot rotation.

constexpr int S_CONST = 2048;
constexpr int D = 1024;
constexpr int G = 16;            // tokens per block
constexpr int NTOK = 8192;
constexpr int JW = 48;           // score columns per group (band width 16+32)
constexpr int JP = 49;           // padded stride
constexpr int NW = 8;            // waves per block

typedef short bf16x8 __attribute__((ext_vector_type(8)));
typedef float f32x4  __attribute__((ext_vector_type(4)));
typedef unsigned int u32x4 __attribute__((ext_vector_type(4)));

// 8 fp32 -> hi/lo bf16 fragments via v_cvt_pk_bf16_f32 (RNE).
// hi = bf16_rne(x); lo = bf16_rne(x - float(hi)).  3 VALU ops/element.
__device__ inline void cvt8(float4 x0, float4 x1, bf16x8& hi, bf16x8& lo) {
    float xs[8] = {x0.x, x0.y, x0.z, x0.w, x1.x, x1.y, x1.z, x1.w};
    u32x4 hv, lv;
    #pragma unroll
    for (int p = 0; p < 4; ++p) {
        float a = xs[2 * p], b = xs[2 * p + 1];
        unsigned hp;
        asm("v_cvt_pk_bf16_f32 %0, %1, %2" : "=v"(hp) : "v"(a), "v"(b));
        float ha = __builtin_bit_cast(float, hp << 16);          // low elem hi
        float hb = __builtin_bit_cast(float, hp & 0xffff0000u);  // high elem hi
        float la = a - ha, lb = b - hb;
        unsigned lp;
        asm("v_cvt_pk_bf16_f32 %0, %1, %2" : "=v"(lp) : "v"(la), "v"(lb));
        hv[p] = hp; lv[p] = lp;
    }
    hi = __builtin_bit_cast(bf16x8, hv);
    lo = __builtin_bit_cast(bf16x8, lv);
}

__global__ __launch_bounds__(512, 4)
void future_encoder_kernel(const float* __restrict__ h,
                           float* __restrict__ out) {
    __shared__ float sc[NW * G * JP];  // per-wave partial scores [w][m][j]
    __shared__ float wm[G * JP];       // final softmax weights  [i][j]

    // XCD swizzle: contiguous chunk per XCD (512 blocks / 8 XCDs)
    int bid = blockIdx.x, nblk = gridDim.x, lb = bid;
    if ((nblk & 7) == 0) {
        int per = nblk >> 3;
        lb = (bid & 7) * per + (bid >> 3);
    }

    const int tid  = threadIdx.x;
    const int w    = tid >> 6;
    const int lane = tid & 63;
    const int t0   = lb * G;                    // first token of group
    const int s0   = t0 & (S_CONST - 1);        // groups never straddle sequences
    const int jlim = (S_CONST - 2) - s0;        // max valid j (>= 14 always)

    // ---------------- Phase 1: scores via MFMA, wave w owns 128-wide D-slice -
    {
        const int d0   = w * 128;
        const int mrow = lane & 15;             // fragment row (token / f-row)
        const int q8   = (lane >> 4) * 8;       // k-chunk within K=32 step

        const float* A = h + (size_t)(t0 + mrow) * D + d0 + q8;
        int r0 = min(t0 +  1 + mrow, NTOK - 1);
        int r1 = min(t0 + 17 + mrow, NTOK - 1);
        int r2 = min(t0 + 33 + mrow, NTOK - 1);
        const float* B0 = h + (size_t)r0 * D + d0 + q8;
        const float* B1 = h + (size_t)r1 * D + d0 + q8;
        const float* B2 = h + (size_t)r2 * D + d0 + q8;

        f32x4 acc[3] = {{0,0,0,0},{0,0,0,0},{0,0,0,0}};

        // preload kk=0 (8 float4 in flight per lane)
        float4 xa0 = *(const float4*)(A),      xa1 = *(const float4*)(A + 4);
        float4 x00 = *(const float4*)(B0),     x01 = *(const float4*)(B0 + 4);
        float4 x10 = *(const float4*)(B1),     x11 = *(const float4*)(B1 + 4);
        float4 x20 = *(const float4*)(B2),     x21 = *(const float4*)(B2 + 4);

        #pragma unroll
        for (int kk = 0; kk < 4; ++kk) {
            float4 na0, na1, n00, n01, n10, n11, n20, n21;
            if (kk < 3) {                       // prefetch next K-step
                const int o = (kk + 1) * 32;
                na0 = *(const float4*)(A  + o); na1 = *(const float4*)(A  + o + 4);
                n00 = *(const float4*)(B0 + o); n01 = *(const float4*)(B0 + o + 4);
                n10 = *(const float4*)(B1 + o); n11 = *(const float4*)(B1 + o + 4);
                n20 = *(const float4*)(B2 + o); n21 = *(const float4*)(B2 + o + 4);
            }

            bf16x8 ah, al;
            cvt8(xa0, xa1, ah, al);

            bf16x8 bh, bl;
            cvt8(x00, x01, bh, bl);
            acc[0] = __builtin_amdgcn_mfma_f32_16x16x32_bf16(ah, bh, acc[0], 0, 0, 0);
            acc[0] = __builtin_amdgcn_mfma_f32_16x16x32_bf16(ah, bl, acc[0], 0, 0, 0);
            acc[0] = __builtin_amdgcn_mfma_f32_16x16x32_bf16(al, bh, acc[0], 0, 0, 0);

            cvt8(x10, x11, bh, bl);
            acc[1] = __builtin_amdgcn_mfma_f32_16x16x32_bf16(ah, bh, acc[1], 0, 0, 0);
            acc[1] = __builtin_amdgcn_mfma_f32_16x16x32_bf16(ah, bl, acc[1], 0, 0, 0);
            acc[1] = __builtin_amdgcn_mfma_f32_16x16x32_bf16(al, bh, acc[1], 0, 0, 0);

            cvt8(x20, x21, bh, bl);
            acc[2] = __builtin_amdgcn_mfma_f32_16x16x32_bf16(ah, bh, acc[2], 0, 0, 0);
            acc[2] = __builtin_amdgcn_mfma_f32_16x16x32_bf16(ah, bl, acc[2], 0, 0, 0);
            acc[2] = __builtin_amdgcn_mfma_f32_16x16x32_bf16(al, bh, acc[2], 0, 0, 0);

            if (kk < 3) {
                xa0 = na0; xa1 = na1;
                x00 = n00; x01 = n01;
                x10 = n10; x11 = n11;
                x20 = n20; x21 = n21;
            }
        }

        // C layout: col = lane&15 (f-row within tile), row = (lane>>4)*4 + reg (token)
        #pragma unroll
        for (int t = 0; t < 3; ++t) {
            #pragma unroll
            for (int r = 0; r < 4; ++r) {
                int m = (lane >> 4) * 4 + r;
                int j = t * 16 + (lane & 15);
                sc[(w * G + m) * JP + j] = acc[t][r];
            }
        }
    }
    __syncthreads();

    // ---------------- Phase 1.5: reduce 8 partials + softmax (waves 0-3) -----
    if (tid < 256) {
        const int i   = tid >> 4;      // token 0..15
        const int sub = tid & 15;      // 16 threads per token

        float v[3];
        #pragma unroll
        for (int c = 0; c < 3; ++c) {
            int j = sub + c * 16;
            float s = 0.f;
            #pragma unroll
            for (int ww = 0; ww < NW; ++ww)
                s += sc[(ww * G + i) * JP + j];
            bool valid = (j >= i) && (j <= i + 31) && (j <= jlim);
            v[c] = valid ? s : -1e9f;
        }
        float mx = fmaxf(v[0], fmaxf(v[1], v[2]));
        #pragma unroll
        for (int d = 1; d < 16; d <<= 1) mx = fmaxf(mx, __shfl_xor(mx, d, 16));

        float e[3];
        float sum = 0.f;
        #pragma unroll
        for (int c = 0; c < 3; ++c) { e[c] = __expf(v[c] - mx); sum += e[c]; }
        #pragma unroll
        for (int d = 1; d < 16; d <<= 1) sum += __shfl_xor(sum, d, 16);

        const bool any = (mx > -5e8f);
        const float inv = any ? (1.0f / sum) : 0.f;
        #pragma unroll
        for (int c = 0; c < 3; ++c) {
            int j = sub + c * 16;
            bool valid = (j >= i) && (j <= i + 31) && (j <= jlim);
            wm[i * JP + j] = valid ? e[c] * inv : 0.f;
        }
    }
    __syncthreads();

    // ---------------- Phase 2: PV fp32 VALU; wave pair splits D --------------
    // Constant 35 steps (j = i0 .. i0+34); weights beyond the valid band are
    // already 0 in wm, row reads clamp to NTOK-1. Fully unrolled, 2-deep
    // prefetch with static 3-slot rotation.
    {
        const int i0   = (w & 3) * 4;           // wave's first token
        const int cc   = (w >> 2) * 2;          // first 256-float chunk
        const int doff = cc * 256 + lane * 4;

        float4 a0[2] = {}, a1[2] = {}, a2[2] = {}, a3[2] = {};
        float4 buf[3][2];

        #define LDJ(slot_, jj_) do {                                            \
            int r_ = min(t0 + 1 + i0 + (jj_), NTOK - 1);                        \
            const float* p_ = h + (size_t)r_ * D + doff;                        \
            buf[slot_][0] = *(const float4*)(p_);                               \
            buf[slot_][1] = *(const float4*)(p_ + 256);                         \
        } while (0)

        LDJ(0, 0);
        LDJ(1, 1);

        #pragma unroll
        for (int jj = 0; jj < 35; ++jj) {
            if (jj + 2 < 35) LDJ((jj + 2) % 3, jj + 2);
            const int j = i0 + jj;
            const float w0 = wm[(i0 + 0) * JP + j];
            const float w1 = wm[(i0 + 1) * JP + j];
            const float w2 = wm[(i0 + 2) * JP + j];
            const float w3 = wm[(i0 + 3) * JP + j];
            const float4 fa = buf[jj % 3][0];
            const float4 fb = buf[jj % 3][1];
            a0[0].x += w0 * fa.x; a0[0].y += w0 * fa.y; a0[0].z += w0 * fa.z; a0[0].w += w0 * fa.w;
            a1[0].x += w1 * fa.x; a1[0].y += w1 * fa.y; a1[0].z += w1 * fa.z; a1[0].w += w1 * fa.w;
            a2[0].x += w2 * fa.x; a2[0].y += w2 * fa.y; a2[0].z += w2 * fa.z; a2[0].w += w2 * fa.w;
            a3[0].x += w3 * fa.x; a3[0].y += w3 * fa.y; a3[0].z += w3 * fa.z; a3[0].w += w3 * fa.w;
            a0[1].x += w0 * fb.x; a0[1].y += w0 * fb.y; a0[1].z += w0 * fb.z; a0[1].w += w0 * fb.w;
            a1[1].x += w1 * fb.x; a1[1].y += w1 * fb.y; a1[1].z += w1 * fb.z; a1[1].w += w1 * fb.w;
            a2[1].x += w2 * fb.x; a2[1].y += w2 * fb.y; a2[1].z += w2 * fb.z; a2[1].w += w2 * fb.w;
            a3[1].x += w3 * fb.x; a3[1].y += w3 * fb.y; a3[1].z += w3 * fb.z; a3[1].w += w3 * fb.w;
        }
        #undef LDJ

        float* o0 = out + (size_t)(t0 + i0) * D + doff;
        *(float4*)(o0 + 0 * D)       = a0[0];
        *(float4*)(o0 + 0 * D + 256) = a0[1];
        *(float4*)(o0 + 1 * D)       = a1[0];
        *(float4*)(o0 + 1 * D + 256) = a1[1];
        *(float4*)(o0 + 2 * D)       = a2[0];
        *(float4*)(o0 + 2 * D + 256) = a2[1];
        *(float4*)(o0 + 3 * D)       = a3[0];
        *(float4*)(o0 + 3 * D + 256) = a3[1];
    }
}

extern "C" void kernel_launch(void* const* d_in, const int* in_sizes, int n_in,
                              void* d_out, int out_size, void* d_ws, size_t ws_size,
                              hipStream_t stream) {
    const float* h = (const float*)d_in[0];
    float* out = (float*)d_out;
    const int ntok = in_sizes[0] / D;        // 8192
    const int blocks = ntok / G;             // 512
    future_encoder_kernel<<<blocks, 512, 0, stream>>>(h, out);
}